// Round 1
// baseline (12804.070 us; speedup 1.0000x reference)
//
#include <hip/hip_runtime.h>

typedef __attribute__((ext_vector_type(8))) short short8;
typedef __attribute__((ext_vector_type(4))) float f32x4;

#define TSTEPS 512
#define NB 64
#define NHID 512
#define BH (NB*NHID)

__device__ __forceinline__ unsigned short f2bf_rne(float f){
  unsigned u = __float_as_uint(f);
  unsigned r = u + 0x7FFFu + ((u >> 16) & 1u);
  return (unsigned short)(r >> 16);
}

// ---------------- max|w| per tensor ----------------
__global__ void maxabs_kernel(const float* __restrict__ w0, const float* __restrict__ w1,
                              const float* __restrict__ w2, const float* __restrict__ w3,
                              const float* __restrict__ w4, const float* __restrict__ w5,
                              unsigned* __restrict__ ctrl)
{
  __shared__ float red[4];
  int tensor = blockIdx.x >> 6;
  int part   = blockIdx.x & 63;
  const float* w = tensor==0?w0:tensor==1?w1:tensor==2?w2:tensor==3?w3:tensor==4?w4:w5;
  float m = 0.f;
  int base = part * 4096;
  for (int i = threadIdx.x; i < 4096; i += 256)
    m = fmaxf(m, fabsf(w[base + i]));
  #pragma unroll
  for (int off = 32; off >= 1; off >>= 1)
    m = fmaxf(m, __shfl_xor(m, off, 64));
  if ((threadIdx.x & 63) == 0) red[threadIdx.x >> 6] = m;
  __syncthreads();
  if (threadIdx.x == 0) {
    m = fmaxf(fmaxf(red[0], red[1]), fmaxf(red[2], red[3]));
    atomicMax(&ctrl[tensor], __float_as_uint(m));
  }
}

// ---------------- persistent GRU scan ----------------
// grid: 256 blocks x 128 threads. block = (bg = blockIdx&3 [16 batches], jg = blockIdx>>2 [8 cols])
// wave0: x-projection (fp32 -> hi/lo bf16 split in-register), tiles T0=[ri|ci], T1=[ni|nh]
// wave1: h-projection (pre-split bf16 hi/lo from global),      tiles T2=[rh|ch], T1=[ni|nh]
__global__ __launch_bounds__(128, 1) void gru_persistent(
    const float* __restrict__ x,
    const float* __restrict__ state,
    const float* __restrict__ w_ri, const float* __restrict__ w_ci,
    const float* __restrict__ w_ni, const float* __restrict__ w_rh,
    const float* __restrict__ w_ch, const float* __restrict__ w_nh,
    const float* __restrict__ bias_r, const float* __restrict__ bias_c,
    const float* __restrict__ bias_ni, const float* __restrict__ bias_nh,
    const unsigned* __restrict__ ctrl, unsigned* __restrict__ bar,
    unsigned short* __restrict__ hhi, unsigned short* __restrict__ hlo,
    float* __restrict__ out)
{
  __shared__ unsigned short Wlds[3*16*512];   // 3 tiles of [n=16][k=512] bf16-int, 48 KiB
  __shared__ float Plds[4*256];               // 4 partial tiles [col16][row16]

  const int tid  = threadIdx.x;
  const int wid  = tid >> 6;
  const int lane = tid & 63;
  const int bg = blockIdx.x & 3;
  const int jg = blockIdx.x >> 2;
  const int bs = bg * 16;

  // scales: s = max(max|w|/127, 1e-8)  (true fp32 division, matches jnp)
  float s[6];
  #pragma unroll
  for (int i = 0; i < 6; i++) s[i] = fmaxf(__uint_as_float(ctrl[i]) / 127.f, 1e-8f);

  // ---- stage quantized int weights (exact in bf16) into LDS, XOR-swizzled ----
  {
    const float* tsrc[3][2]   = {{w_ri, w_ci}, {w_ni, w_nh}, {w_rh, w_ch}};
    const float  tscale[3][2] = {{s[0], s[1]}, {s[2], s[5]}, {s[3], s[4]}};
    for (int c = tid; c < 3072; c += 128) {        // 3072 chunks of 8 shorts
      int t   = c >> 10;
      int rem = c & 1023;
      int n   = rem >> 6;
      int kc  = rem & 63;                          // k-chunk, 8 elems
      const float* src = tsrc[t][n >> 3];
      float sc = tscale[t][n >> 3];
      int col = (jg << 3) + (n & 7);
      short8 q;
      #pragma unroll
      for (int j = 0; j < 8; j++) {
        float wv = src[(size_t)(kc*8 + j) * 512 + col];
        float d  = wv / sc;                        // fp32 division, matches reference
        d = fminf(fmaxf(d, -127.f), 127.f);
        float r = rintf(d);                        // round-half-even == jnp.round
        q[j] = (short)(unsigned short)(__float_as_uint(r) >> 16);  // exact bf16 int
      }
      unsigned byteoff = (unsigned)(t*16384 + n*1024 + (((unsigned)(kc << 4)) ^ ((unsigned)((n & 7) << 4))));
      *(short8*)((char*)Wlds + byteoff) = q;
    }
  }
  __syncthreads();

  // ---- h0 init (hi/lo split of state) by jg==0 blocks ----
  if (jg == 0) {
    for (int i = tid; i < 16*512; i += 128) {
      int idx = (bs + (i >> 9)) * 512 + (i & 511);
      float v = state[idx];
      unsigned short hb = (unsigned short)(__float_as_uint(v) >> 16);
      float hf = __uint_as_float((unsigned)hb << 16);
      hhi[idx] = hb;
      hlo[idx] = f2bf_rne(v - hf);
    }
  }

  int phase = 0;
  // barrier phase 1: h0 visible to all 64 WGs of this bg
  {
    ++phase;
    __threadfence();
    __syncthreads();
    if (tid == 0) {
      __hip_atomic_fetch_add(bar + bg*16, 1u, __ATOMIC_RELEASE, __HIP_MEMORY_SCOPE_AGENT);
      unsigned target = 64u * (unsigned)phase;
      long spins = 0;
      while (__hip_atomic_load(bar + bg*16, __ATOMIC_ACQUIRE, __HIP_MEMORY_SCOPE_AGENT) < target) {
        __builtin_amdgcn_s_sleep(1);
        if (++spins > 200000000L) break;
      }
    }
    __syncthreads();
  }

  // per-thread epilogue constants: one (b, j) element owned for all 512 steps
  const int jl = tid & 7;
  const int bl = tid >> 3;
  const int jglob = (jg << 3) + jl;
  const int bglob = bs + bl;
  const float brv  = bias_r[jglob], bcv = bias_c[jglob];
  const float bniv = bias_ni[jglob], bnhv = bias_nh[jglob];
  float hreg = state[bglob*512 + jglob];

  const int n  = lane & 15;
  const int kg = lane >> 4;
  const unsigned swz = (unsigned)((n & 7) << 4);
  const char* WB = (const char*)Wlds;

  for (int t = 0; t < TSTEPS; ++t) {
    const int par = t & 1;
    const int nxt = par ^ 1;
    f32x4 accA = {0.f, 0.f, 0.f, 0.f};
    f32x4 accB = {0.f, 0.f, 0.f, 0.f};

    if (wid == 0) {
      // x @ [Wri|Wci] and x @ [Wni|Wnh] ; split x -> hi/lo bf16 in-register
      const float* xs = x + ((size_t)t*NB + bs) * 512 + (size_t)n * 512;
      #pragma unroll 4
      for (int it = 0; it < 16; ++it) {
        const float* p = xs + it*32 + kg*8;
        f32x4 v0 = *(const f32x4*)p;
        f32x4 v1 = *(const f32x4*)(p + 4);
        short8 ahi, alo;
        #pragma unroll
        for (int i = 0; i < 4; i++) {
          unsigned u0 = __float_as_uint(v0[i]);
          unsigned short h0 = (unsigned short)(u0 >> 16);
          ahi[i] = (short)h0;
          alo[i] = (short)f2bf_rne(v0[i] - __uint_as_float((unsigned)h0 << 16));
          unsigned u1 = __float_as_uint(v1[i]);
          unsigned short h1 = (unsigned short)(u1 >> 16);
          ahi[i+4] = (short)h1;
          alo[i+4] = (short)f2bf_rne(v1[i] - __uint_as_float((unsigned)h1 << 16));
        }
        unsigned kb = ((unsigned)(it*64 + kg*16)) ^ swz;
        short8 bA = *(const short8*)(WB + 0*16384 + n*1024 + kb);
        short8 bB = *(const short8*)(WB + 1*16384 + n*1024 + kb);
        accA = __builtin_amdgcn_mfma_f32_16x16x32_bf16(ahi, bA, accA, 0, 0, 0);
        accA = __builtin_amdgcn_mfma_f32_16x16x32_bf16(alo, bA, accA, 0, 0, 0);
        accB = __builtin_amdgcn_mfma_f32_16x16x32_bf16(ahi, bB, accB, 0, 0, 0);
        accB = __builtin_amdgcn_mfma_f32_16x16x32_bf16(alo, bB, accB, 0, 0, 0);
      }
    } else {
      // h @ [Wrh|Wch] and h @ [Wni|Wnh] ; h pre-split bf16 hi/lo, double-buffered
      const unsigned short* ph = hhi + par*BH + (size_t)(bs + n) * 512;
      const unsigned short* pl = hlo + par*BH + (size_t)(bs + n) * 512;
      #pragma unroll 4
      for (int it = 0; it < 16; ++it) {
        int ke = it*32 + kg*8;
        short8 ahi = *(const short8*)(ph + ke);
        short8 alo = *(const short8*)(pl + ke);
        unsigned kb = ((unsigned)(it*64 + kg*16)) ^ swz;
        short8 bA = *(const short8*)(WB + 2*16384 + n*1024 + kb);
        short8 bB = *(const short8*)(WB + 1*16384 + n*1024 + kb);
        accA = __builtin_amdgcn_mfma_f32_16x16x32_bf16(ahi, bA, accA, 0, 0, 0);
        accA = __builtin_amdgcn_mfma_f32_16x16x32_bf16(alo, bA, accA, 0, 0, 0);
        accB = __builtin_amdgcn_mfma_f32_16x16x32_bf16(ahi, bB, accB, 0, 0, 0);
        accB = __builtin_amdgcn_mfma_f32_16x16x32_bf16(alo, bB, accB, 0, 0, 0);
      }
    }

    // partials: P[tile][col=n][row]  (D layout: col=lane&15, row=kg*4+i)
    {
      int pA = (wid == 0) ? 0 : 2;
      int pB = (wid == 0) ? 1 : 3;
      *(f32x4*)&Plds[pA*256 + n*16 + kg*4] = accA;
      *(f32x4*)&Plds[pB*256 + n*16 + kg*4] = accB;
    }
    __syncthreads();

    // epilogue: one (b,j) element per thread
    float rx  = Plds[0*256 + jl*16 + bl];        // x @ w_ri
    float cx  = Plds[0*256 + (jl+8)*16 + bl];    // x @ w_ci
    float nix = Plds[1*256 + jl*16 + bl];        // x @ w_ni
    float rhp = Plds[2*256 + jl*16 + bl];        // h @ w_rh
    float chp = Plds[2*256 + (jl+8)*16 + bl];    // h @ w_ch
    float nhp = Plds[3*256 + (jl+8)*16 + bl];    // h @ w_nh

    float pre_r = s[0]*rx + s[3]*rhp + brv;
    float pre_c = s[1]*cx + s[4]*chp + bcv;
    float gni   = s[2]*nix + bniv;
    float gnh   = s[5]*nhp + bnhv;

    float sgr = 1.f / (1.f + expf(-pre_r));
    float rg  = rintf(sgr * 255.f) / 255.f;
    float sgc = 1.f / (1.f + expf(-pre_c));
    float cg  = rintf(sgc * 255.f) / 255.f;
    float tg  = tanhf(gni + rg * gnh);
    float ng  = rintf(tg * 127.f) / 127.f;
    float hy  = ng + cg * (hreg - ng);
    hreg = hy;

    out[(size_t)t*BH + (size_t)bglob*512 + jglob] = hy;
    if (t == TSTEPS-1) out[(size_t)TSTEPS*BH + (size_t)bglob*512 + jglob] = hy;

    {
      unsigned short hb = (unsigned short)(__float_as_uint(hy) >> 16);
      float hf = __uint_as_float((unsigned)hb << 16);
      int hidx = nxt*BH + bglob*512 + jglob;
      hhi[hidx] = hb;
      hlo[hidx] = f2bf_rne(hy - hf);
    }

    // per-batch-group barrier (64 WGs), monotone phase counter
    ++phase;
    __threadfence();
    __syncthreads();
    if (tid == 0) {
      __hip_atomic_fetch_add(bar + bg*16, 1u, __ATOMIC_RELEASE, __HIP_MEMORY_SCOPE_AGENT);
      unsigned target = 64u * (unsigned)phase;
      long spins = 0;
      while (__hip_atomic_load(bar + bg*16, __ATOMIC_ACQUIRE, __HIP_MEMORY_SCOPE_AGENT) < target) {
        __builtin_amdgcn_s_sleep(1);
        if (++spins > 200000000L) break;
      }
    }
    __syncthreads();
  }
}

extern "C" void kernel_launch(void* const* d_in, const int* in_sizes, int n_in,
                              void* d_out, int out_size, void* d_ws, size_t ws_size,
                              hipStream_t stream) {
  const float* x     = (const float*)d_in[0];
  const float* state = (const float*)d_in[1];
  const float* w_ri  = (const float*)d_in[2];
  const float* w_ci  = (const float*)d_in[3];
  const float* w_ni  = (const float*)d_in[4];
  const float* w_rh  = (const float*)d_in[5];
  const float* w_ch  = (const float*)d_in[6];
  const float* w_nh  = (const float*)d_in[7];
  const float* b_r   = (const float*)d_in[8];
  const float* b_c   = (const float*)d_in[9];
  const float* b_ni  = (const float*)d_in[10];
  const float* b_nh  = (const float*)d_in[11];

  unsigned* ctrl = (unsigned*)d_ws;            // [0..5] max|w| bits
  unsigned* bar  = ctrl + 16;                  // 4 counters, 64B apart
  unsigned short* hhi = (unsigned short*)((char*)d_ws + 512);   // [2][BH]
  unsigned short* hlo = hhi + 2*BH;                             // [2][BH]
  float* out = (float*)d_out;

  hipMemsetAsync(d_ws, 0, 512, stream);
  maxabs_kernel<<<384, 256, 0, stream>>>(w_ri, w_ci, w_ni, w_rh, w_ch, w_nh, ctrl);
  gru_persistent<<<256, 128, 0, stream>>>(x, state, w_ri, w_ci, w_ni, w_rh, w_ch, w_nh,
                                          b_r, b_c, b_ni, b_nh, ctrl, bar, hhi, hlo, out);
}

// Round 4
// 3257.520 us; speedup vs baseline: 3.9306x; 3.9306x over previous
//
#include <hip/hip_runtime.h>

typedef __attribute__((ext_vector_type(8))) short short8;
typedef __attribute__((ext_vector_type(4))) short s16x4;
typedef __attribute__((ext_vector_type(4))) float f32x4;

#define TSTEPS 512
#define NB 64
#define NHID 512
#define BH (NB*NHID)

__device__ __forceinline__ unsigned short f2bf_rne(float f){
  unsigned u = __float_as_uint(f);
  unsigned r = u + 0x7FFFu + ((u >> 16) & 1u);
  return (unsigned short)(r >> 16);
}

// ---------------- max|w| per tensor ----------------
__global__ void maxabs_kernel(const float* __restrict__ w0, const float* __restrict__ w1,
                              const float* __restrict__ w2, const float* __restrict__ w3,
                              const float* __restrict__ w4, const float* __restrict__ w5,
                              unsigned* __restrict__ ctrl)
{
  __shared__ float red[4];
  int tensor = blockIdx.x >> 6;
  int part   = blockIdx.x & 63;
  const float* w = tensor==0?w0:tensor==1?w1:tensor==2?w2:tensor==3?w3:tensor==4?w4:w5;
  float m = 0.f;
  int base = part * 4096;
  for (int i = threadIdx.x; i < 4096; i += 256)
    m = fmaxf(m, fabsf(w[base + i]));
  #pragma unroll
  for (int off = 32; off >= 1; off >>= 1)
    m = fmaxf(m, __shfl_xor(m, off, 64));
  if ((threadIdx.x & 63) == 0) red[threadIdx.x >> 6] = m;
  __syncthreads();
  if (threadIdx.x == 0) {
    m = fmaxf(fmaxf(red[0], red[1]), fmaxf(red[2], red[3]));
    atomicMax(&ctrl[tensor], __float_as_uint(m));
  }
}

// ---------------- persistent GRU scan ----------------
// grid: 256 blocks x 128 threads. block = (bg = blockIdx&3 [16 batches], jg = blockIdx>>2 [8 cols])
// wave0: x-projection (fp32 -> hi/lo bf16 split in-register) — overlaps barrier wait
// wave1: waits for h_t visibility, then h-projection
// All cross-WG data (hhi/hlo) moves via relaxed agent-scope atomics so NO acquire/release
// cache writeback/invalidate is ever needed in the loop.
__global__ __launch_bounds__(128, 1) void gru_persistent(
    const float* __restrict__ x,
    const float* __restrict__ state,
    const float* __restrict__ w_ri, const float* __restrict__ w_ci,
    const float* __restrict__ w_ni, const float* __restrict__ w_rh,
    const float* __restrict__ w_ch, const float* __restrict__ w_nh,
    const float* __restrict__ bias_r, const float* __restrict__ bias_c,
    const float* __restrict__ bias_ni, const float* __restrict__ bias_nh,
    const unsigned* __restrict__ ctrl, unsigned* __restrict__ bar,
    unsigned short* __restrict__ hhi, unsigned short* __restrict__ hlo,
    float* __restrict__ out)
{
  __shared__ unsigned short Wlds[3*16*512];   // 3 tiles of [n=16][k=512] bf16-int, 48 KiB
  __shared__ float Plds[4*256];               // 4 partial tiles [col16][row16]

  const int tid  = threadIdx.x;
  const int wid  = tid >> 6;
  const int lane = tid & 63;
  const int bg = blockIdx.x & 3;
  const int jg = blockIdx.x >> 2;
  const int bs = bg * 16;
  unsigned* barp = bar + bg*16;

  // scales: s = max(max|w|/127, 1e-8)  (true fp32 division, matches jnp)
  float s[6];
  #pragma unroll
  for (int i = 0; i < 6; i++) s[i] = fmaxf(__uint_as_float(ctrl[i]) / 127.f, 1e-8f);

  // ---- stage quantized int weights (exact in bf16) into LDS, XOR-swizzled ----
  {
    const float* tsrc[3][2]   = {{w_ri, w_ci}, {w_ni, w_nh}, {w_rh, w_ch}};
    const float  tscale[3][2] = {{s[0], s[1]}, {s[2], s[5]}, {s[3], s[4]}};
    for (int c = tid; c < 3072; c += 128) {        // 3072 chunks of 8 shorts
      int t   = c >> 10;
      int rem = c & 1023;
      int n   = rem >> 6;
      int kc  = rem & 63;                          // k-chunk, 8 elems
      const float* src = tsrc[t][n >> 3];
      float sc = tscale[t][n >> 3];
      int col = (jg << 3) + (n & 7);
      short8 q;
      #pragma unroll
      for (int j = 0; j < 8; j++) {
        float wv = src[(size_t)(kc*8 + j) * 512 + col];
        float d  = wv / sc;                        // fp32 division, matches reference
        d = fminf(fmaxf(d, -127.f), 127.f);
        float r = rintf(d);                        // round-half-even == jnp.round
        q[j] = (short)(unsigned short)(__float_as_uint(r) >> 16);  // exact bf16 int
      }
      unsigned byteoff = (unsigned)(t*16384 + n*1024 + (((unsigned)(kc << 4)) ^ ((unsigned)((n & 7) << 4))));
      *(short8*)((char*)Wlds + byteoff) = q;
    }
  }

  // ---- h0 init (hi/lo split of state) by jg==0 blocks, coherent stores ----
  if (jg == 0) {
    for (int i = tid; i < 16*512; i += 128) {
      int idx = (bs + (i >> 9)) * 512 + (i & 511);
      float v = state[idx];
      unsigned short hb = (unsigned short)(__float_as_uint(v) >> 16);
      float hf = __uint_as_float((unsigned)hb << 16);
      __hip_atomic_store(&hhi[idx], hb, __ATOMIC_RELAXED, __HIP_MEMORY_SCOPE_AGENT);
      __hip_atomic_store(&hlo[idx], f2bf_rne(v - hf), __ATOMIC_RELAXED, __HIP_MEMORY_SCOPE_AGENT);
    }
  }

  // arrival #1: h0 stored. __syncthreads drains vmcnt(0) for every thread first.
  __syncthreads();
  if (tid == 0)
    __hip_atomic_fetch_add(barp, 1u, __ATOMIC_RELAXED, __HIP_MEMORY_SCOPE_AGENT);

  // per-thread epilogue constants: one (b, j) element owned for all 512 steps
  const int jl = tid & 7;
  const int bl = tid >> 3;
  const int jglob = (jg << 3) + jl;
  const int bglob = bs + bl;
  const float brv  = bias_r[jglob], bcv = bias_c[jglob];
  const float bniv = bias_ni[jglob], bnhv = bias_nh[jglob];
  float hreg = state[bglob*512 + jglob];

  const int n  = lane & 15;
  const int kg = lane >> 4;
  const unsigned swz = (unsigned)((n & 7) << 4);
  const char* WB = (const char*)Wlds;

  for (int t = 0; t < TSTEPS; ++t) {
    const int par = t & 1;
    const int nxt = par ^ 1;
    f32x4 accA = {0.f, 0.f, 0.f, 0.f};
    f32x4 accB = {0.f, 0.f, 0.f, 0.f};

    if (wid == 0) {
      // x @ [Wri|Wci] and x @ [Wni|Wnh] ; split x -> hi/lo bf16 in-register.
      // No h dependence: runs concurrently with wave1's barrier spin.
      const float* xs = x + ((size_t)t*NB + bs) * 512 + (size_t)n * 512;
      #pragma unroll 4
      for (int it = 0; it < 16; ++it) {
        const float* p = xs + it*32 + kg*8;
        f32x4 v0 = *(const f32x4*)p;
        f32x4 v1 = *(const f32x4*)(p + 4);
        short8 ahi, alo;
        #pragma unroll
        for (int i = 0; i < 4; i++) {
          unsigned u0 = __float_as_uint(v0[i]);
          unsigned short h0 = (unsigned short)(u0 >> 16);
          ahi[i] = (short)h0;
          alo[i] = (short)f2bf_rne(v0[i] - __uint_as_float((unsigned)h0 << 16));
          unsigned u1 = __float_as_uint(v1[i]);
          unsigned short h1 = (unsigned short)(u1 >> 16);
          ahi[i+4] = (short)h1;
          alo[i+4] = (short)f2bf_rne(v1[i] - __uint_as_float((unsigned)h1 << 16));
        }
        unsigned kb = ((unsigned)(it*64 + kg*16)) ^ swz;
        short8 bA = *(const short8*)(WB + 0*16384 + n*1024 + kb);
        short8 bB = *(const short8*)(WB + 1*16384 + n*1024 + kb);
        accA = __builtin_amdgcn_mfma_f32_16x16x32_bf16(ahi, bA, accA, 0, 0, 0);
        accA = __builtin_amdgcn_mfma_f32_16x16x32_bf16(alo, bA, accA, 0, 0, 0);
        accB = __builtin_amdgcn_mfma_f32_16x16x32_bf16(ahi, bB, accB, 0, 0, 0);
        accB = __builtin_amdgcn_mfma_f32_16x16x32_bf16(alo, bB, accB, 0, 0, 0);
      }
      *(f32x4*)&Plds[0*256 + n*16 + kg*4] = accA;
      *(f32x4*)&Plds[1*256 + n*16 + kg*4] = accB;
    } else {
      // wait until all 64 WGs of this bg published h_t (relaxed spin, no cache inv)
      {
        unsigned target = 64u * (unsigned)(t + 1);
        long spins = 0;
        while (__hip_atomic_load(barp, __ATOMIC_RELAXED, __HIP_MEMORY_SCOPE_AGENT) < target) {
          __builtin_amdgcn_s_sleep(1);
          if (++spins > 10000000L) break;
        }
        asm volatile("" ::: "memory");
        __builtin_amdgcn_sched_barrier(0);
      }
      // h @ [Wrh|Wch] and h @ [Wni|Wnh] ; h read via coherent 8B atomic loads
      const unsigned long long* ph = (const unsigned long long*)(hhi + (size_t)par*BH + (size_t)(bs + n) * 512);
      const unsigned long long* pl = (const unsigned long long*)(hlo + (size_t)par*BH + (size_t)(bs + n) * 512);
      #pragma unroll 4
      for (int it = 0; it < 16; ++it) {
        int ke4 = (it*32 + kg*8) >> 2;             // index in 8B units
        unsigned long long h0 = __hip_atomic_load(ph + ke4,     __ATOMIC_RELAXED, __HIP_MEMORY_SCOPE_AGENT);
        unsigned long long h1 = __hip_atomic_load(ph + ke4 + 1, __ATOMIC_RELAXED, __HIP_MEMORY_SCOPE_AGENT);
        unsigned long long l0 = __hip_atomic_load(pl + ke4,     __ATOMIC_RELAXED, __HIP_MEMORY_SCOPE_AGENT);
        unsigned long long l1 = __hip_atomic_load(pl + ke4 + 1, __ATOMIC_RELAXED, __HIP_MEMORY_SCOPE_AGENT);
        union { unsigned long long u; s16x4 s; } ch0, ch1, cl0, cl1;
        ch0.u = h0; ch1.u = h1; cl0.u = l0; cl1.u = l1;
        short8 ahi = {ch0.s[0],ch0.s[1],ch0.s[2],ch0.s[3], ch1.s[0],ch1.s[1],ch1.s[2],ch1.s[3]};
        short8 alo = {cl0.s[0],cl0.s[1],cl0.s[2],cl0.s[3], cl1.s[0],cl1.s[1],cl1.s[2],cl1.s[3]};
        unsigned kb = ((unsigned)(it*64 + kg*16)) ^ swz;
        short8 bA = *(const short8*)(WB + 2*16384 + n*1024 + kb);
        short8 bB = *(const short8*)(WB + 1*16384 + n*1024 + kb);
        accA = __builtin_amdgcn_mfma_f32_16x16x32_bf16(ahi, bA, accA, 0, 0, 0);
        accA = __builtin_amdgcn_mfma_f32_16x16x32_bf16(alo, bA, accA, 0, 0, 0);
        accB = __builtin_amdgcn_mfma_f32_16x16x32_bf16(ahi, bB, accB, 0, 0, 0);
        accB = __builtin_amdgcn_mfma_f32_16x16x32_bf16(alo, bB, accB, 0, 0, 0);
      }
      *(f32x4*)&Plds[2*256 + n*16 + kg*4] = accA;
      *(f32x4*)&Plds[3*256 + n*16 + kg*4] = accB;
    }
    __syncthreads();

    // epilogue: one (b,j) element per thread
    float rx  = Plds[0*256 + jl*16 + bl];        // x @ w_ri
    float cx  = Plds[0*256 + (jl+8)*16 + bl];    // x @ w_ci
    float nix = Plds[1*256 + jl*16 + bl];        // x @ w_ni
    float rhp = Plds[2*256 + jl*16 + bl];        // h @ w_rh
    float chp = Plds[2*256 + (jl+8)*16 + bl];    // h @ w_ch
    float nhp = Plds[3*256 + (jl+8)*16 + bl];    // h @ w_nh

    float pre_r = s[0]*rx + s[3]*rhp + brv;
    float pre_c = s[1]*cx + s[4]*chp + bcv;
    float gni   = s[2]*nix + bniv;
    float gnh   = s[5]*nhp + bnhv;

    float sgr = 1.f / (1.f + expf(-pre_r));
    float rg  = rintf(sgr * 255.f) / 255.f;
    float sgc = 1.f / (1.f + expf(-pre_c));
    float cg  = rintf(sgc * 255.f) / 255.f;
    float tg  = tanhf(gni + rg * gnh);
    float ng  = rintf(tg * 127.f) / 127.f;
    float hy  = ng + cg * (hreg - ng);
    hreg = hy;

    __builtin_nontemporal_store(hy, &out[(size_t)t*BH + (size_t)bglob*512 + jglob]);
    if (t == TSTEPS-1)
      __builtin_nontemporal_store(hy, &out[(size_t)TSTEPS*BH + (size_t)bglob*512 + jglob]);

    {
      unsigned short hb = (unsigned short)(__float_as_uint(hy) >> 16);
      float hf = __uint_as_float((unsigned)hb << 16);
      int hidx = nxt*BH + bglob*512 + jglob;
      __hip_atomic_store(&hhi[hidx], hb, __ATOMIC_RELAXED, __HIP_MEMORY_SCOPE_AGENT);
      __hip_atomic_store(&hlo[hidx], f2bf_rne(hy - hf), __ATOMIC_RELAXED, __HIP_MEMORY_SCOPE_AGENT);
    }

    // arrival: __syncthreads' built-in s_waitcnt vmcnt(0) drain orders every
    // thread's coherent h stores before tid0's counter increment.
    __syncthreads();
    if (tid == 0)
      __hip_atomic_fetch_add(barp, 1u, __ATOMIC_RELAXED, __HIP_MEMORY_SCOPE_AGENT);
  }
}

extern "C" void kernel_launch(void* const* d_in, const int* in_sizes, int n_in,
                              void* d_out, int out_size, void* d_ws, size_t ws_size,
                              hipStream_t stream) {
  const float* x     = (const float*)d_in[0];
  const float* state = (const float*)d_in[1];
  const float* w_ri  = (const float*)d_in[2];
  const float* w_ci  = (const float*)d_in[3];
  const float* w_ni  = (const float*)d_in[4];
  const float* w_rh  = (const float*)d_in[5];
  const float* w_ch  = (const float*)d_in[6];
  const float* w_nh  = (const float*)d_in[7];
  const float* b_r   = (const float*)d_in[8];
  const float* b_c   = (const float*)d_in[9];
  const float* b_ni  = (const float*)d_in[10];
  const float* b_nh  = (const float*)d_in[11];

  unsigned* ctrl = (unsigned*)d_ws;            // [0..5] max|w| bits
  unsigned* bar  = ctrl + 16;                  // 4 counters, 64B apart
  unsigned short* hhi = (unsigned short*)((char*)d_ws + 512);   // [2][BH]
  unsigned short* hlo = hhi + 2*BH;                             // [2][BH]
  float* out = (float*)d_out;

  (void)hipMemsetAsync(d_ws, 0, 512, stream);
  maxabs_kernel<<<384, 256, 0, stream>>>(w_ri, w_ci, w_ni, w_rh, w_ch, w_nh, ctrl);
  gru_persistent<<<256, 128, 0, stream>>>(x, state, w_ri, w_ci, w_ni, w_rh, w_ch, w_nh,
                                          b_r, b_c, b_ni, b_nh, ctrl, bar, hhi, hlo, out);
}